// Round 7
// baseline (214.086 us; speedup 1.0000x reference)
//
#include <hip/hip_runtime.h>
#include <hip/hip_bf16.h>
#include <math.h>
#include <float.h>

// Problem constants
#define BSZ 16
#define SEQ 4096
#define HID 768
#define H4  192      // HID/4
#define NM  128      // mentions per batch
#define NSPAN 256    // 2*NM endpoint slots per batch
#define ENT 256
#define NTOT 2048    // BSZ*NM
#define SC  64       // sequence chunk size
#define NCH 64       // SEQ/SC
#define LROWS 8      // rows per fused ev+loss block

// ---------------------------------------------------------------------------
// Kernel A (prep):
//   blocks 0..255  : gather 8 label-embedding rows each -> LET[k][j] transposed
//   blocks 256..351: transpose linear_w [ENT][HID] -> WT [HID][ENT]
//   block 256 t0   : zero the loss completion counter
// ---------------------------------------------------------------------------
__global__ __launch_bounds__(256) void prep_kernel(
    const float* __restrict__ lw, float* __restrict__ WT,
    const float* __restrict__ table, const int* __restrict__ labels,
    float* __restrict__ LET, unsigned int* __restrict__ counter) {
  int bid = blockIdx.x, t = threadIdx.x;
  if (bid < 256) {
    __shared__ float lds[8][ENT + 4];  // 260 floats/row: 16B-aligned rows, banks spread
    int j0 = bid * 8;
    int r = t >> 5, q = t & 31;  // 8 rows x 32 threads
    int j = j0 + r;
    int lab = labels[(j >> 7) * 256 + (j & 127)];  // labels[b][0][m]
    const float4* row4 = reinterpret_cast<const float4*>(table + (size_t)lab * ENT);
    float4 v0 = row4[q];
    float4 v1 = row4[q + 32];
    *reinterpret_cast<float4*>(&lds[r][q * 4]) = v0;
    *reinterpret_cast<float4*>(&lds[r][128 + q * 4]) = v1;
    __syncthreads();
    // write LET[k][j0+jj]: k = pass*32 + (t>>3), jj = t&7
    int jj = t & 7, kk = t >> 3;  // kk 0..31
#pragma unroll
    for (int pass = 0; pass < 8; ++pass) {
      int k = pass * 32 + kk;
      LET[(size_t)k * NTOT + j0 + jj] = lds[jj][k];
    }
  } else {
    if (bid == 256 && t == 0) *counter = 0u;
    for (int idx = (bid - 256) * 256 + t; idx < ENT * HID; idx += 96 * 256) {
      int k = idx / ENT, e = idx % ENT;  // WT[k][e] = lw[e][k]
      WT[idx] = lw[e * HID + k];
    }
  }
}

// ---------------------------------------------------------------------------
// Kernel 1: chunked scan over sequence_output (unchanged — near BW floor).
// ---------------------------------------------------------------------------
__global__ __launch_bounds__(192) void span_scan_kernel(
    const float* __restrict__ seq, const int* __restrict__ spans,
    float* __restrict__ W, float* __restrict__ P) {
  int b = blockIdx.x / NCH;
  int c = blockIdx.x % NCH;
  int t = threadIdx.x;  // 0..191

  __shared__ int head[SC + 1];
  __shared__ int nxt[NSPAN];
  __shared__ unsigned int maskw[2];
  __shared__ int has_end;
  for (int i = t; i < SC + 1; i += 192) head[i] = -1;
  if (t < 2) maskw[t] = 0u;
  if (t == 0) has_end = 0;
  __syncthreads();
  for (int j = t; j < NSPAN; j += 192) {
    int e = spans[b * NSPAN + j];  // endpoint in [0, SEQ]
    int ch = e >> 6; if (ch > NCH - 1) ch = NCH - 1;
    if (ch == c) {
      int off = e - c * SC;  // [0, SC]
      nxt[j] = atomicExch(&head[off], j);
      if (off < SC) atomicOr(&maskw[off >> 5], 1u << (off & 31));
      else has_end = 1;
    }
  }
  __syncthreads();
  unsigned long long mask =
      ((unsigned long long)maskw[1] << 32) | maskw[0];
  int emit_end = has_end;

  const float4* seq4 =
      reinterpret_cast<const float4*>(seq) + (size_t)(b * SEQ + c * SC) * H4 + t;
  float4* W4 = reinterpret_cast<float4*>(W);
  float4 acc = make_float4(0.f, 0.f, 0.f, 0.f);
#pragma unroll 8
  for (int s = 0; s < SC; ++s) {
    if (mask & (1ull << s)) {  // wave-uniform, usually false
      for (int p = head[s]; p != -1; p = nxt[p]) {
        W4[(size_t)(b * NSPAN + p) * H4 + t] = acc;
      }
    }
    float4 v = seq4[(size_t)s * H4];
    acc.x += v.x; acc.y += v.y; acc.z += v.z; acc.w += v.w;
  }
  if (emit_end) {
    for (int p = head[SC]; p != -1; p = nxt[p]) {
      W4[(size_t)(b * NSPAN + p) * H4 + t] = acc;
    }
  }
  reinterpret_cast<float4*>(P)[(size_t)(b * NCH + c) * H4 + t] = acc;
}

// ---------------------------------------------------------------------------
// Kernel 2: exclusive prefix over chunk sums (batched loads, 16 blocks).
// ---------------------------------------------------------------------------
__global__ __launch_bounds__(192) void chunk_prefix_kernel(float* __restrict__ P) {
  int b = blockIdx.x;   // 0..15
  int h = threadIdx.x;  // 0..191
  float4* P4 = reinterpret_cast<float4*>(P) + (size_t)b * NCH * H4 + h;
  float4 run = make_float4(0.f, 0.f, 0.f, 0.f);
  for (int cb = 0; cb < NCH; cb += 16) {
    float4 v[16];
#pragma unroll
    for (int i = 0; i < 16; ++i) v[i] = P4[(size_t)(cb + i) * H4];
#pragma unroll
    for (int i = 0; i < 16; ++i) {
      P4[(size_t)(cb + i) * H4] = run;
      run.x += v[i].x; run.y += v[i].y; run.z += v[i].z; run.w += v[i].w;
    }
  }
}

// ---------------------------------------------------------------------------
// Kernel 3 (fused): mention vectors -> entity GEMV -> logits rows -> loss.
// 256 blocks x 1024 threads (16 waves/CU = 4 waves/SIMD: latency-hiding TLP).
// Thread (g = t>>8, ct = t&255):
//   EV phase  : rows 2g, 2g+1, column ct.
//   Loss phase: 8 rows x 2 columns (g*512 + {0,256} + ct).
// ---------------------------------------------------------------------------
__global__ __launch_bounds__(1024) void ev_loss_kernel(
    const float* __restrict__ W, const float* __restrict__ P,
    const int* __restrict__ spans, const float* __restrict__ WT,
    const float* __restrict__ bias, const float* __restrict__ LET,
    const int* __restrict__ labels, float* __restrict__ perrow,
    unsigned int* __restrict__ counter, float* __restrict__ out) {
  int t = threadIdx.x;
  int i0 = blockIdx.x * LROWS;
  int g = t >> 8, ct = t & 255;

  __shared__ float mv[LROWS][HID];
  __shared__ float evs[LROWS][ENT];
  __shared__ float red[LROWS][16];
  __shared__ float diag[LROWS];

  // ---- stage mention vectors (padded-cumsum diff / len) ----
  const float4* W4 = reinterpret_cast<const float4*>(W);
  const float4* P4 = reinterpret_cast<const float4*>(P);
  for (int q = t; q < LROWS * H4; q += 1024) {
    int r = q / H4, h = q - r * H4;
    int bm = i0 + r;
    int b = bm >> 7, m = bm & (NM - 1);
    int e0 = spans[bm * 2], e1 = spans[bm * 2 + 1];
    int c0 = e0 >> 6; if (c0 > NCH - 1) c0 = NCH - 1;
    int c1 = e1 >> 6; if (c1 > NCH - 1) c1 = NCH - 1;
    float4 p0 = P4[(size_t)(b * NCH + c0) * H4 + h];
    float4 p1 = P4[(size_t)(b * NCH + c1) * H4 + h];
    float4 w0 = W4[(size_t)(b * NSPAN + 2 * m) * H4 + h];
    float4 w1 = W4[(size_t)(b * NSPAN + 2 * m + 1) * H4 + h];
    int len = e1 - e0;
    float inv = len > 0 ? 1.f / (float)len : 0.f;  // len==0 -> 0 (nan_to_num)
    float4 s4;
    s4.x = ((p1.x + w1.x) - (p0.x + w0.x)) * inv;
    s4.y = ((p1.y + w1.y) - (p0.y + w0.y)) * inv;
    s4.z = ((p1.z + w1.z) - (p0.z + w0.z)) * inv;
    s4.w = ((p1.w + w1.w) - (p0.w + w0.w)) * inv;
    reinterpret_cast<float4*>(&mv[r][0])[h] = s4;
  }
  __syncthreads();

  // ---- entity GEMV: rows 2g, 2g+1 at column ct ----
  {
    int r0 = 2 * g, r1 = 2 * g + 1;
    float acc0 = 0.f, acc1 = 0.f;
    for (int k4 = 0; k4 < HID; k4 += 4) {
      float4 m0 = *reinterpret_cast<const float4*>(&mv[r0][k4]);  // broadcast
      float4 m1 = *reinterpret_cast<const float4*>(&mv[r1][k4]);
      float wv0 = WT[(size_t)(k4 + 0) * ENT + ct];
      float wv1 = WT[(size_t)(k4 + 1) * ENT + ct];
      float wv2 = WT[(size_t)(k4 + 2) * ENT + ct];
      float wv3 = WT[(size_t)(k4 + 3) * ENT + ct];
      acc0 += m0.x * wv0 + m0.y * wv1 + m0.z * wv2 + m0.w * wv3;
      acc1 += m1.x * wv0 + m1.y * wv1 + m1.z * wv2 + m1.w * wv3;
    }
    float bv = bias[ct];
    acc0 += bv; acc1 += bv;
    evs[r0][ct] = acc0;
    evs[r1][ct] = acc1;
    out[1 + (size_t)(i0 + r0) * ENT + ct] = acc0;
    out[1 + (size_t)(i0 + r1) * ENT + ct] = acc1;
  }
  __syncthreads();

  // ---- logits + per-row log-softmax ----
  float acc[LROWS][2];
#pragma unroll
  for (int r = 0; r < LROWS; ++r) { acc[r][0] = 0.f; acc[r][1] = 0.f; }

  const float* letp = LET + (size_t)g * 512 + ct;  // columns g*512+ct, +256
  float lvA[4][2], lvB[4][2];
#pragma unroll
  for (int kk = 0; kk < 4; ++kk) {
    lvA[kk][0] = letp[(size_t)kk * NTOT];
    lvA[kk][1] = letp[(size_t)kk * NTOT + 256];
  }

  for (int k8 = 0; k8 < ENT; k8 += 8) {
    // prefetch next quad into lvB
#pragma unroll
    for (int kk = 0; kk < 4; ++kk) {
      lvB[kk][0] = letp[(size_t)(k8 + 4 + kk) * NTOT];
      lvB[kk][1] = letp[(size_t)(k8 + 4 + kk) * NTOT + 256];
    }
    // consume lvA (k8..k8+3)
    {
      float4 ef[LROWS];
#pragma unroll
      for (int r = 0; r < LROWS; ++r)
        ef[r] = *reinterpret_cast<const float4*>(&evs[r][k8]);  // broadcast b128
#pragma unroll
      for (int r = 0; r < LROWS; ++r) {
        acc[r][0] += ef[r].x * lvA[0][0]; acc[r][1] += ef[r].x * lvA[0][1];
        acc[r][0] += ef[r].y * lvA[1][0]; acc[r][1] += ef[r].y * lvA[1][1];
        acc[r][0] += ef[r].z * lvA[2][0]; acc[r][1] += ef[r].z * lvA[2][1];
        acc[r][0] += ef[r].w * lvA[3][0]; acc[r][1] += ef[r].w * lvA[3][1];
      }
    }
    // prefetch following quad into lvA (&255 wrap: last prefetch unread)
#pragma unroll
    for (int kk = 0; kk < 4; ++kk) {
      lvA[kk][0] = letp[(size_t)((k8 + 8 + kk) & 255) * NTOT];
      lvA[kk][1] = letp[(size_t)((k8 + 8 + kk) & 255) * NTOT + 256];
    }
    // consume lvB (k8+4..k8+7)
    {
      float4 ef[LROWS];
#pragma unroll
      for (int r = 0; r < LROWS; ++r)
        ef[r] = *reinterpret_cast<const float4*>(&evs[r][k8 + 4]);
#pragma unroll
      for (int r = 0; r < LROWS; ++r) {
        acc[r][0] += ef[r].x * lvB[0][0]; acc[r][1] += ef[r].x * lvB[0][1];
        acc[r][0] += ef[r].y * lvB[1][0]; acc[r][1] += ef[r].y * lvB[1][1];
        acc[r][0] += ef[r].z * lvB[2][0]; acc[r][1] += ef[r].z * lvB[2][1];
        acc[r][0] += ef[r].w * lvB[3][0]; acc[r][1] += ef[r].w * lvB[3][1];
      }
    }
  }

  // diagonal logits — compile-time acc indices (rule #20)
#pragma unroll
  for (int r = 0; r < LROWS; ++r) {
    int i = i0 + r;
    int tdiag = ((i >> 9) << 8) | (i & 255);  // g = i>>9, ct = i&255
    int ccdiag = (i >> 8) & 1;
#pragma unroll
    for (int cc = 0; cc < 2; ++cc) {
      if (t == tdiag && cc == ccdiag) diag[r] = acc[r][cc];
    }
  }

  int lane = t & 63, wid = t >> 6;  // 16 waves
  // row maxes
#pragma unroll
  for (int r = 0; r < LROWS; ++r) {
    float m = fmaxf(acc[r][0], acc[r][1]);
    for (int o = 32; o >= 1; o >>= 1) m = fmaxf(m, __shfl_xor(m, o));
    if (lane == 0) red[r][wid] = m;
  }
  __syncthreads();
  float rowmax[LROWS];
#pragma unroll
  for (int r = 0; r < LROWS; ++r) {
    float m = red[r][0];
#pragma unroll
    for (int wv = 1; wv < 16; ++wv) m = fmaxf(m, red[r][wv]);
    rowmax[r] = m;
  }
  __syncthreads();
  // row exp-sums
#pragma unroll
  for (int r = 0; r < LROWS; ++r) {
    float s = expf(acc[r][0] - rowmax[r]) + expf(acc[r][1] - rowmax[r]);
    for (int o = 32; o >= 1; o >>= 1) s += __shfl_xor(s, o);
    if (lane == 0) red[r][wid] = s;
  }
  __syncthreads();
  if (t < LROWS) {
    int r = t;
    float s = 0.f;
#pragma unroll
    for (int wv = 0; wv < 16; ++wv) s += red[r][wv];
    perrow[i0 + r] = (logf(s) + rowmax[r]) - diag[r];
  }

  // ---- fused finalize: last block reduces perrow -> out[0] ----
  __threadfence();
  __syncthreads();
  __shared__ unsigned int ticket;
  if (t == 0) ticket = atomicAdd(counter, 1u);
  __syncthreads();
  if (ticket == (unsigned)(gridDim.x - 1)) {
    __threadfence();
    float s = 0.f, cnt = 0.f;
    for (int i = t; i < NTOT; i += 1024) {
      int status = labels[(i >> 7) * 256 + 128 + (i & 127)];  // labels[b][1][m]
      if (status >= 0) { s += perrow[i]; cnt += 1.f; }
    }
    __shared__ float rs[1024], rc[1024];
    rs[t] = s; rc[t] = cnt;
    __syncthreads();
    for (int o = 512; o > 0; o >>= 1) {
      if (t < o) { rs[t] += rs[t + o]; rc[t] += rc[t + o]; }
      __syncthreads();
    }
    if (t == 0) {
      float L = rc[0] > 0.f ? rs[0] / rc[0] : 0.f;
      if (isnan(L)) L = 0.f;
      if (isinf(L)) L = L > 0.f ? FLT_MAX : -FLT_MAX;
      out[0] = L;
    }
  }
}

// ---------------------------------------------------------------------------
extern "C" void kernel_launch(void* const* d_in, const int* in_sizes, int n_in,
                              void* d_out, int out_size, void* d_ws,
                              size_t ws_size, hipStream_t stream) {
  const float* seq   = (const float*)d_in[0];  // [16,4096,768]
  const float* lw    = (const float*)d_in[1];  // [256,768]
  const float* lb    = (const float*)d_in[2];  // [256]
  const float* table = (const float*)d_in[3];  // [50000,256]
  const int* spans   = (const int*)d_in[4];    // [16,128,2]
  const int* labels  = (const int*)d_in[5];    // [16,2,128]
  float* out = (float*)d_out;                  // [1 + 16*128*256]
  float* ws = (float*)d_ws;

  // workspace layout (floats)
  float* W      = ws;                              // [16][256][768]
  float* P      = W + (size_t)BSZ * NSPAN * HID;   // [16][64][768]
  float* WT     = P + (size_t)BSZ * NCH * HID;     // [768][256]
  float* LET    = WT + (size_t)HID * ENT;          // [256][2048]
  float* perrow = LET + (size_t)ENT * NTOT;        // [2048]
  unsigned int* counter = (unsigned int*)(perrow + NTOT);

  prep_kernel<<<352, 256, 0, stream>>>(lw, WT, table, labels, LET, counter);
  span_scan_kernel<<<BSZ * NCH, 192, 0, stream>>>(seq, spans, W, P);
  chunk_prefix_kernel<<<BSZ, 192, 0, stream>>>(P);
  ev_loss_kernel<<<NTOT / LROWS, 1024, 0, stream>>>(
      W, P, spans, WT, lb, LET, labels, perrow, counter, out);
}

// Round 8
// 196.694 us; speedup vs baseline: 1.0884x; 1.0884x over previous
//
#include <hip/hip_runtime.h>
#include <hip/hip_bf16.h>
#include <math.h>
#include <float.h>

// Problem constants
#define BSZ 16
#define SEQ 4096
#define HID 768
#define H4  192      // HID/4
#define NM  128      // mentions per batch
#define NSPAN 256    // 2*NM endpoint slots per batch
#define ENT 256
#define NTOT 2048    // BSZ*NM
#define SC  64       // sequence chunk size
#define NCH 64       // SEQ/SC

// ---------------------------------------------------------------------------
// Kernel A (prep):
//   blocks 0..255  : gather 8 label-embedding rows each -> LET[k][j] transposed
//   blocks 256..351: transpose linear_w [ENT][HID] -> WT [HID][ENT]
//   block 256 t0   : zero the loss completion counter
// ---------------------------------------------------------------------------
__global__ __launch_bounds__(256) void prep_kernel(
    const float* __restrict__ lw, float* __restrict__ WT,
    const float* __restrict__ table, const int* __restrict__ labels,
    float* __restrict__ LET, unsigned int* __restrict__ counter) {
  int bid = blockIdx.x, t = threadIdx.x;
  if (bid < 256) {
    __shared__ float lds[8][ENT + 4];
    int j0 = bid * 8;
    int r = t >> 5, q = t & 31;  // 8 rows x 32 threads
    int j = j0 + r;
    int lab = labels[(j >> 7) * 256 + (j & 127)];  // labels[b][0][m]
    const float4* row4 = reinterpret_cast<const float4*>(table + (size_t)lab * ENT);
    float4 v0 = row4[q];
    float4 v1 = row4[q + 32];
    *reinterpret_cast<float4*>(&lds[r][q * 4]) = v0;
    *reinterpret_cast<float4*>(&lds[r][128 + q * 4]) = v1;
    __syncthreads();
    int jj = t & 7, kk = t >> 3;  // kk 0..31
#pragma unroll
    for (int pass = 0; pass < 8; ++pass) {
      int k = pass * 32 + kk;
      LET[(size_t)k * NTOT + j0 + jj] = lds[jj][k];
    }
  } else {
    if (bid == 256 && t == 0) *counter = 0u;
    for (int idx = (bid - 256) * 256 + t; idx < ENT * HID; idx += 96 * 256) {
      int k = idx / ENT, e = idx % ENT;  // WT[k][e] = lw[e][k]
      WT[idx] = lw[e * HID + k];
    }
  }
}

// ---------------------------------------------------------------------------
// Kernel 1: chunked scan over sequence_output (near HBM floor — unchanged).
// ---------------------------------------------------------------------------
__global__ __launch_bounds__(192) void span_scan_kernel(
    const float* __restrict__ seq, const int* __restrict__ spans,
    float* __restrict__ W, float* __restrict__ P) {
  int b = blockIdx.x / NCH;
  int c = blockIdx.x % NCH;
  int t = threadIdx.x;  // 0..191

  __shared__ int head[SC + 1];
  __shared__ int nxt[NSPAN];
  __shared__ unsigned int maskw[2];
  __shared__ int has_end;
  for (int i = t; i < SC + 1; i += 192) head[i] = -1;
  if (t < 2) maskw[t] = 0u;
  if (t == 0) has_end = 0;
  __syncthreads();
  for (int j = t; j < NSPAN; j += 192) {
    int e = spans[b * NSPAN + j];  // endpoint in [0, SEQ]
    int ch = e >> 6; if (ch > NCH - 1) ch = NCH - 1;
    if (ch == c) {
      int off = e - c * SC;  // [0, SC]
      nxt[j] = atomicExch(&head[off], j);
      if (off < SC) atomicOr(&maskw[off >> 5], 1u << (off & 31));
      else has_end = 1;
    }
  }
  __syncthreads();
  unsigned long long mask =
      ((unsigned long long)maskw[1] << 32) | maskw[0];
  int emit_end = has_end;

  const float4* seq4 =
      reinterpret_cast<const float4*>(seq) + (size_t)(b * SEQ + c * SC) * H4 + t;
  float4* W4 = reinterpret_cast<float4*>(W);
  float4 acc = make_float4(0.f, 0.f, 0.f, 0.f);
#pragma unroll 8
  for (int s = 0; s < SC; ++s) {
    if (mask & (1ull << s)) {  // wave-uniform, usually false
      for (int p = head[s]; p != -1; p = nxt[p]) {
        W4[(size_t)(b * NSPAN + p) * H4 + t] = acc;
      }
    }
    float4 v = seq4[(size_t)s * H4];
    acc.x += v.x; acc.y += v.y; acc.z += v.z; acc.w += v.w;
  }
  if (emit_end) {
    for (int p = head[SC]; p != -1; p = nxt[p]) {
      W4[(size_t)(b * NSPAN + p) * H4 + t] = acc;
    }
  }
  reinterpret_cast<float4*>(P)[(size_t)(b * NCH + c) * H4 + t] = acc;
}

// ---------------------------------------------------------------------------
// Kernel 2: exclusive prefix over chunk sums (batched loads, 16 blocks).
// ---------------------------------------------------------------------------
__global__ __launch_bounds__(192) void chunk_prefix_kernel(float* __restrict__ P) {
  int b = blockIdx.x;   // 0..15
  int h = threadIdx.x;  // 0..191
  float4* P4 = reinterpret_cast<float4*>(P) + (size_t)b * NCH * H4 + h;
  float4 run = make_float4(0.f, 0.f, 0.f, 0.f);
  for (int cb = 0; cb < NCH; cb += 16) {
    float4 v[16];
#pragma unroll
    for (int i = 0; i < 16; ++i) v[i] = P4[(size_t)(cb + i) * H4];
#pragma unroll
    for (int i = 0; i < 16; ++i) {
      P4[(size_t)(cb + i) * H4] = run;
      run.x += v[i].x; run.y += v[i].y; run.z += v[i].z; run.w += v[i].w;
    }
  }
}

// ---------------------------------------------------------------------------
// Kernel 3: entity GEMV, 2D register tile.
// Grid 512 blocks (4 rows each) x 256 thr; thread = 1 row (rg=t>>6) x 4 cols
// (float4 WT loads; one mv b128 per 4 k's -> FMA:LDS = 16:1). Dbuf prefetch.
// ---------------------------------------------------------------------------
__global__ __launch_bounds__(256) void ev_gemm_kernel(
    const float* __restrict__ W, const float* __restrict__ P,
    const int* __restrict__ spans, const float* __restrict__ WT,
    const float* __restrict__ bias, float* __restrict__ EVa,
    float* __restrict__ out) {
  int t = threadIdx.x;
  int i0 = blockIdx.x * 4;
  __shared__ float mv[4][HID];

  const float4* W4 = reinterpret_cast<const float4*>(W);
  const float4* P4 = reinterpret_cast<const float4*>(P);
  for (int q = t; q < 4 * H4; q += 256) {
    int r = q / H4, h = q - r * H4;
    int bm = i0 + r;
    int b = bm >> 7, m = bm & (NM - 1);
    int e0 = spans[bm * 2], e1 = spans[bm * 2 + 1];
    int c0 = e0 >> 6; if (c0 > NCH - 1) c0 = NCH - 1;
    int c1 = e1 >> 6; if (c1 > NCH - 1) c1 = NCH - 1;
    float4 p0 = P4[(size_t)(b * NCH + c0) * H4 + h];
    float4 p1 = P4[(size_t)(b * NCH + c1) * H4 + h];
    float4 w0 = W4[(size_t)(b * NSPAN + 2 * m) * H4 + h];
    float4 w1 = W4[(size_t)(b * NSPAN + 2 * m + 1) * H4 + h];
    int len = e1 - e0;
    float inv = len > 0 ? 1.f / (float)len : 0.f;  // len==0 -> 0 (nan_to_num)
    float4 s4;
    s4.x = ((p1.x + w1.x) - (p0.x + w0.x)) * inv;
    s4.y = ((p1.y + w1.y) - (p0.y + w0.y)) * inv;
    s4.z = ((p1.z + w1.z) - (p0.z + w0.z)) * inv;
    s4.w = ((p1.w + w1.w) - (p0.w + w0.w)) * inv;
    reinterpret_cast<float4*>(&mv[r][0])[h] = s4;
  }
  __syncthreads();

  int rg = t >> 6, ct = t & 63;  // row-group (=wave), col-group of 4
  const float* mrow = &mv[rg][0];
  const float4* WT4 = reinterpret_cast<const float4*>(WT);  // [k][64] float4

  float4 acc = make_float4(0.f, 0.f, 0.f, 0.f);
  float4 wvA[4], wvB[4];
#pragma unroll
  for (int kk = 0; kk < 4; ++kk) wvA[kk] = WT4[(size_t)kk * 64 + ct];

#define EV_FMA(MQ, WV)                                                        \
  acc.x += (MQ).x * WV[0].x + (MQ).y * WV[1].x + (MQ).z * WV[2].x + (MQ).w * WV[3].x; \
  acc.y += (MQ).x * WV[0].y + (MQ).y * WV[1].y + (MQ).z * WV[2].y + (MQ).w * WV[3].y; \
  acc.z += (MQ).x * WV[0].z + (MQ).y * WV[1].z + (MQ).z * WV[2].z + (MQ).w * WV[3].z; \
  acc.w += (MQ).x * WV[0].w + (MQ).y * WV[1].w + (MQ).z * WV[2].w + (MQ).w * WV[3].w;

  for (int k8 = 0; k8 < HID; k8 += 8) {
#pragma unroll
    for (int kk = 0; kk < 4; ++kk) wvB[kk] = WT4[(size_t)(k8 + 4 + kk) * 64 + ct];
    float4 mqa = *reinterpret_cast<const float4*>(&mrow[k8]);
    EV_FMA(mqa, wvA)
    int ka = (k8 + 8 < HID) ? (k8 + 8) : 0;  // wrapped dummy prefetch
#pragma unroll
    for (int kk = 0; kk < 4; ++kk) wvA[kk] = WT4[(size_t)(ka + kk) * 64 + ct];
    float4 mqb = *reinterpret_cast<const float4*>(&mrow[k8 + 4]);
    EV_FMA(mqb, wvB)
  }
#undef EV_FMA

  float4 bv = reinterpret_cast<const float4*>(bias)[ct];
  acc.x += bv.x; acc.y += bv.y; acc.z += bv.z; acc.w += bv.w;
  int row = i0 + rg;
  reinterpret_cast<float4*>(EVa)[(size_t)row * 64 + ct] = acc;
  float* op = out + 1 + (size_t)row * ENT + ct * 4;
  op[0] = acc.x; op[1] = acc.y; op[2] = acc.z; op[3] = acc.w;
}

// ---------------------------------------------------------------------------
// Kernel 4: logits partials. 2D grid: 128 row-tiles (16 rows) x 4 col-tiles
// (512 cols) = 512 blocks x 256 thr. Thread = 4 rows (rg=wave) x 8 cols
// (2 float4 LET loads/k; 4 evs b128/quad -> FMA:LDS = 32:1). Per-block
// partial (rowmax, sumexp, diag) -> exact LSE combine in last-block ticket.
// ---------------------------------------------------------------------------
#define FMA8(R, EK, L0, L1)                                    \
  acc[R][0] += (EK) * (L0).x; acc[R][1] += (EK) * (L0).y;      \
  acc[R][2] += (EK) * (L0).z; acc[R][3] += (EK) * (L0).w;      \
  acc[R][4] += (EK) * (L1).x; acc[R][5] += (EK) * (L1).y;      \
  acc[R][6] += (EK) * (L1).z; acc[R][7] += (EK) * (L1).w;

#define FMA_ROW(R, EF, LV)                                     \
  FMA8(R, (EF).x, LV[0], LV[1]) FMA8(R, (EF).y, LV[2], LV[3])  \
  FMA8(R, (EF).z, LV[4], LV[5]) FMA8(R, (EF).w, LV[6], LV[7])

#define LOSS_CONSUME(LV, KQ)                                                 \
  {                                                                          \
    float4 ef0 = *reinterpret_cast<const float4*>(&evs[rg * 4 + 0][KQ]);     \
    float4 ef1 = *reinterpret_cast<const float4*>(&evs[rg * 4 + 1][KQ]);     \
    float4 ef2 = *reinterpret_cast<const float4*>(&evs[rg * 4 + 2][KQ]);     \
    float4 ef3 = *reinterpret_cast<const float4*>(&evs[rg * 4 + 3][KQ]);     \
    FMA_ROW(0, ef0, LV) FMA_ROW(1, ef1, LV)                                  \
    FMA_ROW(2, ef2, LV) FMA_ROW(3, ef3, LV)                                  \
  }

#define LOSS_PREFETCH(LV, KQ)                                                \
  {                                                                          \
    _Pragma("unroll")                                                        \
    for (int kk = 0; kk < 4; ++kk) {                                         \
      LV[kk * 2 + 0] = letb[(size_t)((KQ) + kk) * 512];                      \
      LV[kk * 2 + 1] = letb[(size_t)((KQ) + kk) * 512 + 1];                  \
    }                                                                        \
  }

__global__ __launch_bounds__(256) void loss_part_kernel(
    const float* __restrict__ EVa, const float* __restrict__ LET,
    const int* __restrict__ labels, float* __restrict__ Pmax,
    float* __restrict__ Psum, float* __restrict__ Pdiag,
    unsigned int* __restrict__ counter, float* __restrict__ out) {
  int t = threadIdx.x;
  int bid = blockIdx.x;
  int ctile = bid & 3, rtile = bid >> 2;
  int i0 = rtile * 16;
  int rg = t >> 6, ct = t & 63;  // rg == wave id, ct == lane

  __shared__ float evs[16][ENT];
  float4* evs4 = reinterpret_cast<float4*>(&evs[0][0]);
  const float4* src = reinterpret_cast<const float4*>(EVa + (size_t)i0 * ENT);
  for (int q = t; q < 16 * 64; q += 256) evs4[q] = src[q];
  __syncthreads();

  float acc[4][8];
#pragma unroll
  for (int r = 0; r < 4; ++r)
#pragma unroll
    for (int c = 0; c < 8; ++c) acc[r][c] = 0.f;

  // thread cols: ctile*512 + ct*8 .. +7 (two float4s per k)
  const float4* letb =
      reinterpret_cast<const float4*>(LET + (size_t)ctile * 512) + ct * 2;
  float4 lvA[8], lvB[8];
  LOSS_PREFETCH(lvA, 0)
  for (int k8 = 0; k8 < ENT; k8 += 8) {
    LOSS_PREFETCH(lvB, k8 + 4)
    LOSS_CONSUME(lvA, k8)
    LOSS_PREFETCH(lvA, (k8 + 8) & 255)  // wrapped dummy on last iter
    LOSS_CONSUME(lvB, k8 + 4)
  }

  // per-wave softmax partials for rows rg*4+r over this block's 512 cols
#pragma unroll
  for (int r = 0; r < 4; ++r) {
    int i = i0 + rg * 4 + r;
    float m = acc[r][0];
#pragma unroll
    for (int c = 1; c < 8; ++c) m = fmaxf(m, acc[r][c]);
    for (int o = 32; o >= 1; o >>= 1) m = fmaxf(m, __shfl_xor(m, o));
    float s = 0.f;
#pragma unroll
    for (int c = 0; c < 8; ++c) s += expf(acc[r][c] - m);
    for (int o = 32; o >= 1; o >>= 1) s += __shfl_xor(s, o);
    if (ct == 0) {
      Pmax[(i << 2) | ctile] = m;
      Psum[(i << 2) | ctile] = s;
    }
    if ((i >> 9) == ctile) {  // diag col inside this col-tile
      int lc = i & 511;
#pragma unroll
      for (int c = 0; c < 8; ++c) {
        if ((lc >> 3) == ct && (lc & 7) == c) Pdiag[i] = acc[r][c];
      }
    }
  }

  // ---- last-block ticket: exact LSE combine + masked mean ----
  __threadfence();
  __syncthreads();
  __shared__ unsigned int ticket;
  if (t == 0) ticket = atomicAdd(counter, 1u);
  __syncthreads();
  if (ticket == (unsigned)(gridDim.x - 1)) {
    __threadfence();
    float ls = 0.f, cnt = 0.f;
    for (int i = t; i < NTOT; i += 256) {
      float4 mx = reinterpret_cast<const float4*>(Pmax)[i];
      float4 sm = reinterpret_cast<const float4*>(Psum)[i];
      float M = fmaxf(fmaxf(mx.x, mx.y), fmaxf(mx.z, mx.w));
      float S = sm.x * expf(mx.x - M) + sm.y * expf(mx.y - M) +
                sm.z * expf(mx.z - M) + sm.w * expf(mx.w - M);
      float pr = (logf(S) + M) - Pdiag[i];
      int status = labels[(i >> 7) * 256 + 128 + (i & 127)];  // labels[b][1][m]
      if (status >= 0) { ls += pr; cnt += 1.f; }
    }
    __shared__ float rs[256], rc[256];
    rs[t] = ls; rc[t] = cnt;
    __syncthreads();
    for (int o = 128; o > 0; o >>= 1) {
      if (t < o) { rs[t] += rs[t + o]; rc[t] += rc[t + o]; }
      __syncthreads();
    }
    if (t == 0) {
      float L = rc[0] > 0.f ? rs[0] / rc[0] : 0.f;
      if (isnan(L)) L = 0.f;
      if (isinf(L)) L = L > 0.f ? FLT_MAX : -FLT_MAX;
      out[0] = L;
    }
  }
}

// ---------------------------------------------------------------------------
extern "C" void kernel_launch(void* const* d_in, const int* in_sizes, int n_in,
                              void* d_out, int out_size, void* d_ws,
                              size_t ws_size, hipStream_t stream) {
  const float* seq   = (const float*)d_in[0];  // [16,4096,768]
  const float* lw    = (const float*)d_in[1];  // [256,768]
  const float* lb    = (const float*)d_in[2];  // [256]
  const float* table = (const float*)d_in[3];  // [50000,256]
  const int* spans   = (const int*)d_in[4];    // [16,128,2]
  const int* labels  = (const int*)d_in[5];    // [16,2,128]
  float* out = (float*)d_out;                  // [1 + 16*128*256]
  float* ws = (float*)d_ws;

  // workspace layout (floats)
  float* W      = ws;                              // [16][256][768]
  float* P      = W + (size_t)BSZ * NSPAN * HID;   // [16][64][768]
  float* WT     = P + (size_t)BSZ * NCH * HID;     // [768][256]
  float* EVa    = WT + (size_t)HID * ENT;          // [2048][256]
  float* LET    = EVa + (size_t)NTOT * ENT;        // [256][2048]
  float* Pmax   = LET + (size_t)ENT * NTOT;        // [2048][4]
  float* Psum   = Pmax + NTOT * 4;                 // [2048][4]
  float* Pdiag  = Psum + NTOT * 4;                 // [2048]
  unsigned int* counter = (unsigned int*)(Pdiag + NTOT);

  prep_kernel<<<352, 256, 0, stream>>>(lw, WT, table, labels, LET, counter);
  span_scan_kernel<<<BSZ * NCH, 192, 0, stream>>>(seq, spans, W, P);
  chunk_prefix_kernel<<<BSZ, 192, 0, stream>>>(P);
  ev_gemm_kernel<<<NTOT / 4, 256, 0, stream>>>(W, P, spans, WT, lb, EVa, out);
  loss_part_kernel<<<512, 256, 0, stream>>>(EVa, LET, labels, Pmax, Psum,
                                            Pdiag, counter, out);
}

// Round 9
// 120.833 us; speedup vs baseline: 1.7718x; 1.6278x over previous
//
#include <hip/hip_runtime.h>
#include <hip/hip_bf16.h>
#include <math.h>
#include <float.h>

// Problem constants
#define BSZ 16
#define SEQ 4096
#define HID 768
#define H4  192      // HID/4
#define NM  128
#define NSPAN 256
#define ENT 256
#define NTOT 2048
#define SC  64
#define NCH 64

typedef __attribute__((ext_vector_type(8))) short bfx8;
typedef __attribute__((ext_vector_type(4))) float f32x4;

static __device__ __forceinline__ unsigned short f2bf(float x) {
  unsigned int u = __float_as_uint(x);
  unsigned int r = (u + 0x7fff + ((u >> 16) & 1)) >> 16;  // RNE
  return (unsigned short)r;
}

// ---------------------------------------------------------------------------
// prep2: convert linear_w -> bf16 LWb [256][768]; gather label embeddings as
// bf16 rows LEb[j][k] (row-major, NO transpose); zero ticket counter.
// ---------------------------------------------------------------------------
__global__ __launch_bounds__(256) void prep2_kernel(
    const float* __restrict__ lw, unsigned short* __restrict__ LWb,
    const float* __restrict__ table, const int* __restrict__ labels,
    unsigned short* __restrict__ LEb, unsigned int* __restrict__ counter) {
  int bid = blockIdx.x, t = threadIdx.x;
  if (bid == 0 && t == 0) *counter = 0u;
  // LW convert (grid-stride over 196608)
  for (int idx = bid * 256 + t; idx < ENT * HID; idx += 128 * 256)
    LWb[idx] = f2bf(lw[idx]);
  // LE gather: 16 rows per block
#pragma unroll
  for (int it = 0; it < 16; ++it) {
    int idx = it * 256 + t;          // 0..4095
    int jr = idx >> 8, e = idx & 255;
    int j = bid * 16 + jr;
    int lab = labels[(j >> 7) * 256 + (j & 127)];  // labels[b][0][m]
    LEb[(size_t)j * 256 + e] = f2bf(table[(size_t)lab * ENT + e]);
  }
}

// ---------------------------------------------------------------------------
// span_scan: chunked scan over sequence_output (HBM-bound, unchanged).
// ---------------------------------------------------------------------------
__global__ __launch_bounds__(192) void span_scan_kernel(
    const float* __restrict__ seq, const int* __restrict__ spans,
    float* __restrict__ W, float* __restrict__ P) {
  int b = blockIdx.x / NCH;
  int c = blockIdx.x % NCH;
  int t = threadIdx.x;

  __shared__ int head[SC + 1];
  __shared__ int nxt[NSPAN];
  __shared__ unsigned int maskw[2];
  __shared__ int has_end;
  for (int i = t; i < SC + 1; i += 192) head[i] = -1;
  if (t < 2) maskw[t] = 0u;
  if (t == 0) has_end = 0;
  __syncthreads();
  for (int j = t; j < NSPAN; j += 192) {
    int e = spans[b * NSPAN + j];
    int ch = e >> 6; if (ch > NCH - 1) ch = NCH - 1;
    if (ch == c) {
      int off = e - c * SC;
      nxt[j] = atomicExch(&head[off], j);
      if (off < SC) atomicOr(&maskw[off >> 5], 1u << (off & 31));
      else has_end = 1;
    }
  }
  __syncthreads();
  unsigned long long mask = ((unsigned long long)maskw[1] << 32) | maskw[0];
  int emit_end = has_end;

  const float4* seq4 =
      reinterpret_cast<const float4*>(seq) + (size_t)(b * SEQ + c * SC) * H4 + t;
  float4* W4 = reinterpret_cast<float4*>(W);
  float4 acc = make_float4(0.f, 0.f, 0.f, 0.f);
#pragma unroll 8
  for (int s = 0; s < SC; ++s) {
    if (mask & (1ull << s)) {
      for (int p = head[s]; p != -1; p = nxt[p]) {
        W4[(size_t)(b * NSPAN + p) * H4 + t] = acc;
      }
    }
    float4 v = seq4[(size_t)s * H4];
    acc.x += v.x; acc.y += v.y; acc.z += v.z; acc.w += v.w;
  }
  if (emit_end) {
    for (int p = head[SC]; p != -1; p = nxt[p]) {
      W4[(size_t)(b * NSPAN + p) * H4 + t] = acc;
    }
  }
  reinterpret_cast<float4*>(P)[(size_t)(b * NCH + c) * H4 + t] = acc;
}

// ---------------------------------------------------------------------------
// chunk_prefix: exclusive prefix over chunk sums (batched loads).
// ---------------------------------------------------------------------------
__global__ __launch_bounds__(192) void chunk_prefix_kernel(float* __restrict__ P) {
  int b = blockIdx.x;
  int h = threadIdx.x;
  float4* P4 = reinterpret_cast<float4*>(P) + (size_t)b * NCH * H4 + h;
  float4 run = make_float4(0.f, 0.f, 0.f, 0.f);
  for (int cb = 0; cb < NCH; cb += 16) {
    float4 v[16];
#pragma unroll
    for (int i = 0; i < 16; ++i) v[i] = P4[(size_t)(cb + i) * H4];
#pragma unroll
    for (int i = 0; i < 16; ++i) {
      P4[(size_t)(cb + i) * H4] = run;
      run.x += v[i].x; run.y += v[i].y; run.z += v[i].z; run.w += v[i].w;
    }
  }
}

// ---------------------------------------------------------------------------
// ev_mfma: EV[2048][256] = MV[2048][768] x LWb^T via 16x16x32 bf16 MFMA.
// Grid 256 blocks x 256 thr: block = 16 rows x 128 cols (bid&1 = col half).
// Stage mv rows (f32 compute -> bf16 LDS, padded rows). Wave w: 2 n-tiles.
// Writes EV f32 to out[1+...] and bf16 to EVb (loss A input).
// ---------------------------------------------------------------------------
#define APAD 776  // 768 + 8 bf16 pad (stride 1552B -> banks spread, 2-way max)
__global__ __launch_bounds__(256) void ev_mfma_kernel(
    const float* __restrict__ W, const float* __restrict__ P,
    const int* __restrict__ spans, const unsigned short* __restrict__ LWb,
    const float* __restrict__ bias, unsigned short* __restrict__ EVb,
    float* __restrict__ out) {
  int t = threadIdx.x;
  int chalf = blockIdx.x & 1;
  int i0 = (blockIdx.x >> 1) * 16;

  __shared__ unsigned short Ab[16][APAD];

  // stage mv rows i0..i0+15 as bf16
  const float4* W4 = reinterpret_cast<const float4*>(W);
  const float4* P4 = reinterpret_cast<const float4*>(P);
  for (int it = 0; it < 12; ++it) {
    int q = it * 256 + t;            // 0..3071
    int r = q / H4, h = q - r * H4;
    int bm = i0 + r;
    int b = bm >> 7, m = bm & (NM - 1);
    int e0 = spans[bm * 2], e1 = spans[bm * 2 + 1];
    int c0 = e0 >> 6; if (c0 > NCH - 1) c0 = NCH - 1;
    int c1 = e1 >> 6; if (c1 > NCH - 1) c1 = NCH - 1;
    float4 p0 = P4[(size_t)(b * NCH + c0) * H4 + h];
    float4 p1 = P4[(size_t)(b * NCH + c1) * H4 + h];
    float4 w0 = W4[(size_t)(b * NSPAN + 2 * m) * H4 + h];
    float4 w1 = W4[(size_t)(b * NSPAN + 2 * m + 1) * H4 + h];
    int len = e1 - e0;
    float inv = len > 0 ? 1.f / (float)len : 0.f;
    unsigned short s0 = f2bf(((p1.x + w1.x) - (p0.x + w0.x)) * inv);
    unsigned short s1 = f2bf(((p1.y + w1.y) - (p0.y + w0.y)) * inv);
    unsigned short s2 = f2bf(((p1.z + w1.z) - (p0.z + w0.z)) * inv);
    unsigned short s3 = f2bf(((p1.w + w1.w) - (p0.w + w0.w)) * inv);
    ushort4 pk; pk.x = s0; pk.y = s1; pk.z = s2; pk.w = s3;
    *reinterpret_cast<ushort4*>(&Ab[r][h * 4]) = pk;
  }
  __syncthreads();

  int w = t >> 6, l = t & 63;
  int lr = l & 15, lg = l >> 4;

  f32x4 acc[2];
  acc[0] = (f32x4)(0.f); acc[1] = (f32x4)(0.f);

  for (int ks = 0; ks < 24; ++ks) {
    bfx8 a = *reinterpret_cast<const bfx8*>(&Ab[lr][ks * 32 + lg * 8]);
#pragma unroll
    for (int nt = 0; nt < 2; ++nt) {
      int col = chalf * 128 + w * 32 + nt * 16 + lr;
      bfx8 bf = *reinterpret_cast<const bfx8*>(
          &LWb[(size_t)col * HID + ks * 32 + lg * 8]);
      acc[nt] = __builtin_amdgcn_mfma_f32_16x16x32_bf16(a, bf, acc[nt], 0, 0, 0);
    }
  }

#pragma unroll
  for (int nt = 0; nt < 2; ++nt) {
    int col = chalf * 128 + w * 32 + nt * 16 + lr;
    float bv = bias[col];
#pragma unroll
    for (int r = 0; r < 4; ++r) {
      int row = i0 + lg * 4 + r;
      float v = acc[nt][r] + bv;
      out[1 + (size_t)row * ENT + col] = v;
      EVb[(size_t)row * ENT + col] = f2bf(v);
    }
  }
}

// ---------------------------------------------------------------------------
// loss_mfma: logits[2048][2048] = EVb x LEb^T via MFMA; per-block softmax
// partials (rowmax, sumexp, diag) over 512-col tile; ticket LSE-combine.
// Grid 512 blocks x 256 thr: rtile=bid>>2 (16 rows), ctile=bid&3 (512 cols).
// Wave w: 8 n-tiles (cols c0 + (w*8+nt)*16).
// ---------------------------------------------------------------------------
__global__ __launch_bounds__(256) void loss_mfma_kernel(
    const unsigned short* __restrict__ EVb, const unsigned short* __restrict__ LEb,
    const int* __restrict__ labels, float* __restrict__ Pmax,
    float* __restrict__ Psum, float* __restrict__ Pdiag,
    unsigned int* __restrict__ counter, float* __restrict__ out) {
  int t = threadIdx.x;
  int bid = blockIdx.x;
  int ctile = bid & 3, rtile = bid >> 2;
  int i0 = rtile * 16, c0 = ctile * 512;

  __shared__ unsigned short Ab[16][264];  // 256 + 8 pad
  __shared__ float redm[4][16], reds[4][16];

  for (int q = t; q < 512; q += 256) {     // 16 rows x 32 short8 chunks
    int r = q >> 5, c8 = q & 31;
    *reinterpret_cast<bfx8*>(&Ab[r][c8 * 8]) =
        *reinterpret_cast<const bfx8*>(&EVb[(size_t)(i0 + r) * ENT + c8 * 8]);
  }
  __syncthreads();

  int w = t >> 6, l = t & 63;
  int lr = l & 15, lg = l >> 4;

  f32x4 acc[8];
#pragma unroll
  for (int nt = 0; nt < 8; ++nt) acc[nt] = (f32x4)(0.f);

  for (int ks = 0; ks < 8; ++ks) {
    bfx8 a = *reinterpret_cast<const bfx8*>(&Ab[lr][ks * 32 + lg * 8]);
#pragma unroll
    for (int nt = 0; nt < 8; ++nt) {
      int col = c0 + (w * 8 + nt) * 16 + lr;
      bfx8 bf = *reinterpret_cast<const bfx8*>(
          &LEb[(size_t)col * ENT + ks * 32 + lg * 8]);
      acc[nt] = __builtin_amdgcn_mfma_f32_16x16x32_bf16(a, bf, acc[nt], 0, 0, 0);
    }
  }

  // softmax partials: lane holds rows lg*4+r (r<4), cols (w*8+nt)*16+lr
  float mrow[4], srow[4];
#pragma unroll
  for (int r = 0; r < 4; ++r) {
    float m = acc[0][r];
#pragma unroll
    for (int nt = 1; nt < 8; ++nt) m = fmaxf(m, acc[nt][r]);
    m = fmaxf(m, __shfl_xor(m, 1));
    m = fmaxf(m, __shfl_xor(m, 2));
    m = fmaxf(m, __shfl_xor(m, 4));
    m = fmaxf(m, __shfl_xor(m, 8));
    mrow[r] = m;
    float s = 0.f;
#pragma unroll
    for (int nt = 0; nt < 8; ++nt) s += expf(acc[nt][r] - m);
    s += __shfl_xor(s, 1);
    s += __shfl_xor(s, 2);
    s += __shfl_xor(s, 4);
    s += __shfl_xor(s, 8);
    srow[r] = s;
  }
  if (lr == 0) {
#pragma unroll
    for (int r = 0; r < 4; ++r) {
      redm[w][lg * 4 + r] = mrow[r];
      reds[w][lg * 4 + r] = srow[r];
    }
  }
  // diag: lane's (row, col) match -> static acc indices
#pragma unroll
  for (int nt = 0; nt < 8; ++nt) {
#pragma unroll
    for (int r = 0; r < 4; ++r) {
      int grow = i0 + lg * 4 + r;
      int gcol = c0 + (w * 8 + nt) * 16 + lr;
      if (gcol == grow) Pdiag[grow] = acc[nt][r];
    }
  }
  __syncthreads();
  if (t < 16) {
    int i = i0 + t;
    float M = redm[0][t];
    M = fmaxf(M, redm[1][t]); M = fmaxf(M, redm[2][t]); M = fmaxf(M, redm[3][t]);
    float S = reds[0][t] * expf(redm[0][t] - M) + reds[1][t] * expf(redm[1][t] - M) +
              reds[2][t] * expf(redm[2][t] - M) + reds[3][t] * expf(redm[3][t] - M);
    Pmax[(i << 2) | ctile] = M;
    Psum[(i << 2) | ctile] = S;
  }

  // ---- last-block ticket: exact LSE combine + masked mean ----
  __threadfence();
  __syncthreads();
  __shared__ unsigned int ticket;
  if (t == 0) ticket = atomicAdd(counter, 1u);
  __syncthreads();
  if (ticket == (unsigned)(gridDim.x - 1)) {
    __threadfence();
    float ls = 0.f, cnt = 0.f;
    for (int i = t; i < NTOT; i += 256) {
      float4 mx = reinterpret_cast<const float4*>(Pmax)[i];
      float4 sm = reinterpret_cast<const float4*>(Psum)[i];
      float M = fmaxf(fmaxf(mx.x, mx.y), fmaxf(mx.z, mx.w));
      float S = sm.x * expf(mx.x - M) + sm.y * expf(mx.y - M) +
                sm.z * expf(mx.z - M) + sm.w * expf(mx.w - M);
      float pr = (logf(S) + M) - Pdiag[i];
      int status = labels[(i >> 7) * 256 + 128 + (i & 127)];
      if (status >= 0) { ls += pr; cnt += 1.f; }
    }
    __shared__ float rs[256], rc[256];
    rs[t] = ls; rc[t] = cnt;
    __syncthreads();
    for (int o = 128; o > 0; o >>= 1) {
      if (t < o) { rs[t] += rs[t + o]; rc[t] += rc[t + o]; }
      __syncthreads();
    }
    if (t == 0) {
      float L = rc[0] > 0.f ? rs[0] / rc[0] : 0.f;
      if (isnan(L)) L = 0.f;
      if (isinf(L)) L = L > 0.f ? FLT_MAX : -FLT_MAX;
      out[0] = L;
    }
  }
}

// ---------------------------------------------------------------------------
extern "C" void kernel_launch(void* const* d_in, const int* in_sizes, int n_in,
                              void* d_out, int out_size, void* d_ws,
                              size_t ws_size, hipStream_t stream) {
  const float* seq   = (const float*)d_in[0];
  const float* lw    = (const float*)d_in[1];
  const float* lb    = (const float*)d_in[2];
  const float* table = (const float*)d_in[3];
  const int* spans   = (const int*)d_in[4];
  const int* labels  = (const int*)d_in[5];
  float* out = (float*)d_out;
  float* ws = (float*)d_ws;

  // workspace layout
  float* W  = ws;                                  // [16][256][768] f32
  float* P  = W + (size_t)BSZ * NSPAN * HID;       // [16][64][768]  f32
  float* Pmax = P + (size_t)BSZ * NCH * HID;       // [2048][4]
  float* Psum = Pmax + NTOT * 4;                   // [2048][4]
  float* Pdiag = Psum + NTOT * 4;                  // [2048]
  unsigned int* counter = (unsigned int*)(Pdiag + NTOT);
  unsigned short* LWb = (unsigned short*)(counter + 4);   // [256][768] bf16
  unsigned short* LEb = LWb + (size_t)ENT * HID;          // [2048][256] bf16
  unsigned short* EVb = LEb + (size_t)NTOT * ENT;         // [2048][256] bf16

  prep2_kernel<<<128, 256, 0, stream>>>(lw, LWb, table, labels, LEb, counter);
  span_scan_kernel<<<BSZ * NCH, 192, 0, stream>>>(seq, spans, W, P);
  chunk_prefix_kernel<<<BSZ, 192, 0, stream>>>(P);
  ev_mfma_kernel<<<256, 256, 0, stream>>>(W, P, spans, LWb, lb, EVb, out);
  loss_mfma_kernel<<<512, 256, 0, stream>>>(EVb, LEb, labels, Pmax, Psum,
                                            Pdiag, counter, out);
}